// Round 6
// baseline (537.251 us; speedup 1.0000x reference)
//
#include <hip/hip_runtime.h>
#include <hip/hip_bf16.h>

typedef __bf16 bf16_t;
typedef __bf16 bf16x8 __attribute__((ext_vector_type(8)));
typedef __bf16 bf16x4 __attribute__((ext_vector_type(4)));
typedef float f32x4 __attribute__((ext_vector_type(4)));

#define NN 50000
#define NE 600000

__device__ __forceinline__ void gload_lds16(const void* g, void* l) {
    __builtin_amdgcn_global_load_lds(
        (const __attribute__((address_space(1))) void*)g,
        (__attribute__((address_space(3))) void*)l, 16, 0, 0);
}

// ---------- converts ----------
// x fp32 -> bf16, and zero degi (saves a memset dispatch)
__global__ void cvt_x_zero(const float* __restrict__ in, bf16_t* __restrict__ out, int n4,
                           int* __restrict__ degi, int nz) {
    int t = blockIdx.x * blockDim.x + threadIdx.x;
    if (t < nz) degi[t] = 0;
    if (t >= n4) return;
    float4 v = ((const float4*)in)[t];
    bf16x4 o; o[0] = (bf16_t)v.x; o[1] = (bf16_t)v.y; o[2] = (bf16_t)v.z; o[3] = (bf16_t)v.w;
    ((bf16x4*)out)[t] = o;
}

// weights: W1/W2 pairs + combined W3 (96x256: rows 0-46 Wl3, 47 zero, 48-94 Wr3, 95 zero)
__global__ void cvt_weights(const float* __restrict__ Wl1, const float* __restrict__ Wr1,
                            const float* __restrict__ Wl2, const float* __restrict__ Wr2,
                            const float* __restrict__ Wl3, const float* __restrict__ Wr3,
                            bf16_t* __restrict__ o1l, bf16_t* __restrict__ o1r,
                            bf16_t* __restrict__ o2l, bf16_t* __restrict__ o2r,
                            bf16_t* __restrict__ o3) {
    int t = blockIdx.x * blockDim.x + threadIdx.x;  // 55296 groups of 4
    bf16x4 o;
    if (t < 49152) {
        const float* in; bf16_t* out; int g;
        if (t < 8192)       { in = Wl1; out = o1l; g = t; }
        else if (t < 16384) { in = Wr1; out = o1r; g = t - 8192; }
        else if (t < 32768) { in = Wl2; out = o2l; g = t - 16384; }
        else                { in = Wr2; out = o2r; g = t - 32768; }
        float4 v = ((const float4*)in)[g];
        o[0] = (bf16_t)v.x; o[1] = (bf16_t)v.y; o[2] = (bf16_t)v.z; o[3] = (bf16_t)v.w;
        ((bf16x4*)out)[g] = o;
    } else if (t < 55296) {
        int g = t - 49152;
        int row = g >> 6, c4 = (g & 63) * 4;  // row in [0,96)
        const float* src = nullptr;
        int srow = 0;
        if (row < 47) { src = Wl3; srow = row; }
        else if (row >= 48 && row < 95) { src = Wr3; srow = row - 48; }
        if (src) {
            float4 v = *(const float4*)(src + srow * 256 + c4);
            o[0] = (bf16_t)v.x; o[1] = (bf16_t)v.y; o[2] = (bf16_t)v.z; o[3] = (bf16_t)v.w;
        } else {
            o[0] = o[1] = o[2] = o[3] = (bf16_t)0.f;
        }
        *(bf16x4*)(o3 + row * 256 + c4) = o;
    }
}

// ---------- CSR build ----------
__global__ void deg_count(const int* __restrict__ ei, int* __restrict__ degi, int E) {
    int e = blockIdx.x * blockDim.x + threadIdx.x;
    if (e < E) atomicAdd(&degi[ei[E + e]], 1);
}

__global__ __launch_bounds__(1024) void scan_blocks(const int* __restrict__ degi,
                                                    int* __restrict__ rowptr,
                                                    float* __restrict__ dinv,
                                                    int* __restrict__ partials, int n) {
    int i = blockIdx.x * 1024 + threadIdx.x;
    int v = (i < n) ? degi[i] : 0;
    int lane = threadIdx.x & 63;
    int w = threadIdx.x >> 6;
    int s = v;
#pragma unroll
    for (int o = 1; o < 64; o <<= 1) {
        int t = __shfl_up(s, o);
        if (lane >= o) s += t;
    }
    __shared__ int wsum[16];
    if (lane == 63) wsum[w] = s;
    __syncthreads();
    if (threadIdx.x < 16) {
        int t = wsum[threadIdx.x];
#pragma unroll
        for (int o = 1; o < 16; o <<= 1) {
            int u = __shfl_up(t, o);
            if ((int)threadIdx.x >= o) t += u;
        }
        wsum[threadIdx.x] = t;
    }
    __syncthreads();
    int incl = s + ((w > 0) ? wsum[w - 1] : 0);
    if (i < n) {
        rowptr[i] = incl - v;
        dinv[i] = 1.0f / fmaxf((float)v, 1.0f);
    }
    if (threadIdx.x == 1023) partials[blockIdx.x] = incl;
}

__global__ void scan_partials(const int* __restrict__ partials, int* __restrict__ blockofs,
                              int* __restrict__ rowptr, int nb, int n) {
    int lane = threadIdx.x;
    int v = (lane < nb) ? partials[lane] : 0;
    int s = v;
#pragma unroll
    for (int o = 1; o < 64; o <<= 1) {
        int t = __shfl_up(s, o);
        if (lane >= o) s += t;
    }
    if (lane < nb) blockofs[lane] = s - v;
    if (lane == 63) rowptr[n] = s;
}

__global__ void add_offsets(int* __restrict__ rowptr, int* __restrict__ cursor,
                            const int* __restrict__ blockofs, int n) {
    int i = blockIdx.x * blockDim.x + threadIdx.x;
    if (i >= n) return;
    int v = rowptr[i] + blockofs[i >> 10];
    rowptr[i] = v;
    cursor[i] = v;
}

__global__ void fill_csr(const int* __restrict__ ei, int* __restrict__ cursor,
                         int* __restrict__ csr_src, int E) {
    int e = blockIdx.x * blockDim.x + threadIdx.x;
    if (e >= E) return;
    int d = ei[E + e];
    int pos = atomicAdd(&cursor[d], 1);
    csr_src[pos] = ei[e];
}

// ---------- XCD-segmented gather aggregations ----------
// Row split into 8 column segments; seg = blockIdx.x & 7 so (round-robin block->XCD
// dispatch) XCD x only touches segment x: per-XCD L2 working set 25.6/8 = 3.2 MB < 4 MB.
// One wave per (node, seg); edge-parallel lanes, shfl_xor reduce.

// C=256 (512B rows): seg = 64B = 4 slices x 16B. 16 edges x 4 lanes.
__global__ __launch_bounds__(256) void gather_agg_256_seg(
    const int* __restrict__ rowptr, const int* __restrict__ csr_src,
    const bf16_t* __restrict__ H, const float* __restrict__ dinv,
    bf16_t* __restrict__ out, int N) {
    int seg = blockIdx.x & 7;
    int node = (blockIdx.x >> 3) * 4 + (threadIdx.x >> 6);
    if (node >= N) return;
    int lane = threadIdx.x & 63;
    int eg = lane >> 2, sl = lane & 3;
    int base_c = seg * 32 + sl * 8;
    int s0 = rowptr[node], s1 = rowptr[node + 1];
    float acc[8] = {0.f, 0.f, 0.f, 0.f, 0.f, 0.f, 0.f, 0.f};
    for (int j = s0; j < s1; j += 16) {
        int e = j + eg;
        if (e < s1) {
            int src = csr_src[e];
            bf16x8 v = *(const bf16x8*)(H + (long)src * 256 + base_c);
#pragma unroll
            for (int i = 0; i < 8; i++) acc[i] += (float)v[i];
        }
    }
#pragma unroll
    for (int m = 4; m <= 32; m <<= 1)
#pragma unroll
        for (int i = 0; i < 8; i++) acc[i] += __shfl_xor(acc[i], m);
    if (eg == 0) {
        float di = dinv[node];
        bf16x8 o;
#pragma unroll
        for (int i = 0; i < 8; i++) o[i] = (bf16_t)(acc[i] * di);
        *(bf16x8*)(out + (long)node * 256 + base_c) = o;
    }
}

// C=128 (256B rows): seg = 32B = 2 slices x 16B. 32 edges x 2 lanes.
__global__ __launch_bounds__(256) void gather_agg_128_seg(
    const int* __restrict__ rowptr, const int* __restrict__ csr_src,
    const bf16_t* __restrict__ X, const float* __restrict__ dinv,
    bf16_t* __restrict__ out, int N) {
    int seg = blockIdx.x & 7;
    int node = (blockIdx.x >> 3) * 4 + (threadIdx.x >> 6);
    if (node >= N) return;
    int lane = threadIdx.x & 63;
    int eg = lane >> 1, sl = lane & 1;
    int base_c = seg * 16 + sl * 8;
    int s0 = rowptr[node], s1 = rowptr[node + 1];
    float acc[8] = {0.f, 0.f, 0.f, 0.f, 0.f, 0.f, 0.f, 0.f};
    for (int j = s0; j < s1; j += 32) {
        int e = j + eg;
        if (e < s1) {
            int src = csr_src[e];
            bf16x8 v = *(const bf16x8*)(X + (long)src * 128 + base_c);
#pragma unroll
            for (int i = 0; i < 8; i++) acc[i] += (float)v[i];
        }
    }
#pragma unroll
    for (int m = 2; m <= 32; m <<= 1)
#pragma unroll
        for (int i = 0; i < 8; i++) acc[i] += __shfl_xor(acc[i], m);
    if (eg == 0) {
        float di = dinv[node];
        bf16x8 o;
#pragma unroll
        for (int i = 0; i < 8; i++) o[i] = (bf16_t)(acc[i] * di);
        *(bf16x8*)(out + (long)node * 128 + base_c) = o;
    }
}

// ---------- LDS-staged MFMA GEMM: 128x128 tile / block, BK=64 slices ----------
template <int KTOT, bool DUAL, bool RELU>
__global__ __launch_bounds__(256) void gemm_lds(
    const bf16_t* __restrict__ A1, const bf16_t* __restrict__ A2,
    const bf16_t* __restrict__ W1, const bf16_t* __restrict__ W2,
    bf16_t* __restrict__ Out, int N, int NOUT) {
    __shared__ bf16_t As[128 * 64];
    __shared__ bf16_t Bs[128 * 64];
    int tid = threadIdx.x;
    int w = tid >> 6, lane = tid & 63;
    int wr = w >> 1, wc = w & 1;
    int rowBase = blockIdx.x * 128;
    int colBase = blockIdx.y * 128;
    int m = lane & 15, q = lane >> 4;

    long aoff[4], boff[4];
    int ldsOff[4];
#pragma unroll
    for (int i = 0; i < 4; i++) {
        int c = w * 256 + i * 64 + lane;
        int r = c >> 3, s = c & 7;
        int gk = (s ^ (r & 7)) << 3;
        aoff[i] = (long)min(rowBase + r, N - 1) * KTOT + gk;
        boff[i] = (long)(colBase + r) * KTOT + gk;
        ldsOff[i] = (w * 4 + i) * 512;
    }

    f32x4 acc[4][4];
#pragma unroll
    for (int a = 0; a < 4; a++)
#pragma unroll
        for (int b = 0; b < 4; b++) acc[a][b] = (f32x4){0.f, 0.f, 0.f, 0.f};

#pragma unroll
    for (int half = 0; half < (DUAL ? 2 : 1); half++) {
        const bf16_t* A = half ? A2 : A1;
        const bf16_t* W = half ? W2 : W1;
#pragma unroll
        for (int k0 = 0; k0 < KTOT; k0 += 64) {
            __syncthreads();
#pragma unroll
            for (int i = 0; i < 4; i++) {
                gload_lds16(A + aoff[i] + k0, As + ldsOff[i]);
                gload_lds16(W + boff[i] + k0, Bs + ldsOff[i]);
            }
            __syncthreads();
#pragma unroll
            for (int ks = 0; ks < 2; ks++) {
                bf16x8 af[4], bfr[4];
#pragma unroll
                for (int rf = 0; rf < 4; rf++) {
                    int r = wr * 64 + rf * 16 + m;
                    int seg = ks * 4 + q;
                    af[rf] = *(const bf16x8*)(As + r * 64 + ((seg ^ (r & 7)) << 3));
                }
#pragma unroll
                for (int cf = 0; cf < 4; cf++) {
                    int r = wc * 64 + cf * 16 + m;
                    int seg = ks * 4 + q;
                    bfr[cf] = *(const bf16x8*)(Bs + r * 64 + ((seg ^ (r & 7)) << 3));
                }
#pragma unroll
                for (int rf = 0; rf < 4; rf++)
#pragma unroll
                    for (int cf = 0; cf < 4; cf++)
                        acc[rf][cf] = __builtin_amdgcn_mfma_f32_16x16x32_bf16(af[rf], bfr[cf], acc[rf][cf], 0, 0, 0);
            }
        }
    }

    int r0 = q * 4;
#pragma unroll
    for (int rf = 0; rf < 4; rf++) {
#pragma unroll
        for (int i = 0; i < 4; i++) {
            int row = rowBase + wr * 64 + rf * 16 + r0 + i;
            if (row >= N) continue;
#pragma unroll
            for (int cf = 0; cf < 4; cf++) {
                float v = acc[rf][cf][i];
                if (RELU) v = fmaxf(v, 0.f);
                Out[(long)row * NOUT + colBase + wc * 64 + cf * 16 + m] = (bf16_t)v;
            }
        }
    }
}

// ---------- direct-load MFMA GEMM (layer 3: combined NOUT=96, bf16 out) ----------
template <int CF>
__global__ __launch_bounds__(256) void gemm_mfma(
    const bf16_t* __restrict__ A1, const bf16_t* __restrict__ W1,
    bf16_t* __restrict__ Out, int N, int K, int NOUT) {
    const int G = NOUT / (16 * CF);
    int lane = threadIdx.x & 63;
    int wid = blockIdx.x * 4 + (threadIdx.x >> 6);
    int rowTile = wid / G;
    int cg = wid - rowTile * G;
    int rowBase = rowTile * 64;
    if (rowBase >= N) return;
    int colBase = cg * 16 * CF;
    int m = lane & 15;
    int kq = (lane >> 4) * 8;

    f32x4 acc[4][CF];
#pragma unroll
    for (int a = 0; a < 4; a++)
#pragma unroll
        for (int b = 0; b < CF; b++) acc[a][b] = (f32x4){0.f, 0.f, 0.f, 0.f};

    long ar[4];
#pragma unroll
    for (int rf = 0; rf < 4; rf++) {
        int r = rowBase + rf * 16 + m;
        ar[rf] = (long)min(r, N - 1) * K;
    }

    for (int k0 = kq; k0 < K; k0 += 32) {
        bf16x8 a[4], b[CF];
#pragma unroll
        for (int rf = 0; rf < 4; rf++) a[rf] = *(const bf16x8*)(A1 + ar[rf] + k0);
#pragma unroll
        for (int cf = 0; cf < CF; cf++)
            b[cf] = *(const bf16x8*)(W1 + (long)(colBase + cf * 16 + m) * K + k0);
#pragma unroll
        for (int rf = 0; rf < 4; rf++)
#pragma unroll
            for (int cf = 0; cf < CF; cf++)
                acc[rf][cf] = __builtin_amdgcn_mfma_f32_16x16x32_bf16(a[rf], b[cf], acc[rf][cf], 0, 0, 0);
    }

    int r0 = (lane >> 4) * 4;
#pragma unroll
    for (int rf = 0; rf < 4; rf++) {
#pragma unroll
        for (int i = 0; i < 4; i++) {
            int row = rowBase + rf * 16 + r0 + i;
            if (row >= N) continue;
#pragma unroll
            for (int cf = 0; cf < CF; cf++)
                Out[(long)row * NOUT + colBase + cf * 16 + m] = (bf16_t)acc[rf][cf][i];
        }
    }
}

// ---------- final: gather TR[:, :48] + dinv + TR[node, 48+lane] + log_softmax ----------
__global__ void final_fused(const int* __restrict__ rowptr, const int* __restrict__ csr_src,
                            const bf16_t* __restrict__ TR, const float* __restrict__ dinv,
                            float* __restrict__ out, int N) {
    int wid = blockIdx.x * (blockDim.x >> 6) + (threadIdx.x >> 6);
    int lane = threadIdx.x & 63;
    if (wid >= N) return;
    int s0 = rowptr[wid], s1 = rowptr[wid + 1];
    float a = 0.f, b = 0.f;
    if (lane < 48) {
        int j = s0;
        for (; j + 3 < s1; j += 4) {
            int sa = csr_src[j], sb = csr_src[j + 1], sc = csr_src[j + 2], sd = csr_src[j + 3];
            a += (float)TR[(long)sa * 96 + lane] + (float)TR[(long)sb * 96 + lane];
            b += (float)TR[(long)sc * 96 + lane] + (float)TR[(long)sd * 96 + lane];
        }
        for (; j < s1; j++) a += (float)TR[(long)csr_src[j] * 96 + lane];
    }
    bool act = lane < 47;
    float v = act ? (a + b) * dinv[wid] + (float)TR[(long)wid * 96 + 48 + lane] : -INFINITY;
    float mx = v;
#pragma unroll
    for (int o = 32; o; o >>= 1) mx = fmaxf(mx, __shfl_xor(mx, o));
    float ex = act ? expf(v - mx) : 0.f;
    float s = ex;
#pragma unroll
    for (int o = 32; o; o >>= 1) s += __shfl_xor(s, o);
    float ls = logf(s);
    if (act) out[(long)wid * 47 + lane] = v - mx - ls;
}

extern "C" void kernel_launch(void* const* d_in, const int* in_sizes, int n_in,
                              void* d_out, int out_size, void* d_ws, size_t ws_size,
                              hipStream_t stream) {
    const float* x   = (const float*)d_in[0];
    const float* Wl1 = (const float*)d_in[1];
    const float* Wr1 = (const float*)d_in[2];
    const float* Wl2 = (const float*)d_in[3];
    const float* Wr2 = (const float*)d_in[4];
    const float* Wl3 = (const float*)d_in[5];
    const float* Wr3 = (const float*)d_in[6];
    const int*   ei  = (const int*)d_in[7];
    float* out = (float*)d_out;
    const int N = NN, E = NE;
    const int NB = (N + 1023) / 1024;

    char* ws = (char*)d_ws;
    size_t off = 0;
    auto carve = [&](size_t bytes) { void* p = ws + off; off = (off + bytes + 255) & ~(size_t)255; return p; };
    int*    degi     = (int*)carve((size_t)N * 4);
    int*    rowptr   = (int*)carve((size_t)(N + 1) * 4);
    int*    cursor   = (int*)carve((size_t)N * 4);
    int*    csr_src  = (int*)carve((size_t)E * 4);
    int*    partials = (int*)carve(64 * 4);
    int*    blockofs = (int*)carve(64 * 4);
    float*  dinv     = (float*)carve((size_t)N * 4);
    bf16_t* aggB     = (bf16_t*)carve((size_t)N * 256 * 2);
    bf16_t* xB       = (bf16_t*)carve((size_t)N * 128 * 2);
    bf16_t* H1       = (bf16_t*)carve((size_t)N * 256 * 2);
    bf16_t* H2       = (bf16_t*)carve((size_t)N * 256 * 2);
    bf16_t* TR       = (bf16_t*)carve((size_t)N * 96 * 2);
    bf16_t* wb1l = (bf16_t*)carve(256 * 128 * 2);
    bf16_t* wb1r = (bf16_t*)carve(256 * 128 * 2);
    bf16_t* wb2l = (bf16_t*)carve(256 * 256 * 2);
    bf16_t* wb2r = (bf16_t*)carve(256 * 256 * 2);
    bf16_t* wb3  = (bf16_t*)carve(96 * 256 * 2);

    // --- converts (+degi zeroing) ---
    cvt_x_zero<<<(N * 32 + 255) / 256, 256, 0, stream>>>(x, xB, N * 32, degi, N);
    cvt_weights<<<216, 256, 0, stream>>>(Wl1, Wr1, Wl2, Wr2, Wl3, Wr3,
                                         wb1l, wb1r, wb2l, wb2r, wb3);

    // --- CSR build ---
    deg_count<<<(E + 255) / 256, 256, 0, stream>>>(ei, degi, E);
    scan_blocks<<<NB, 1024, 0, stream>>>(degi, rowptr, dinv, partials, N);
    scan_partials<<<1, 64, 0, stream>>>(partials, blockofs, rowptr, NB, N);
    add_offsets<<<(N + 255) / 256, 256, 0, stream>>>(rowptr, cursor, blockofs, N);
    fill_csr<<<(E + 255) / 256, 256, 0, stream>>>(ei, cursor, csr_src, E);

    const int RT = (N + 127) / 128;
    const int NCHUNK = (N + 3) / 4;  // 4 nodes (waves) per block

    // --- layer 1 ---
    gather_agg_128_seg<<<NCHUNK * 8, 256, 0, stream>>>(rowptr, csr_src, xB, dinv, aggB, N);
    gemm_lds<128, true, true><<<dim3(RT, 2), 256, 0, stream>>>(aggB, xB, wb1l, wb1r, H1, N, 256);

    // --- layer 2 ---
    gather_agg_256_seg<<<NCHUNK * 8, 256, 0, stream>>>(rowptr, csr_src, H1, dinv, aggB, N);
    gemm_lds<256, true, true><<<dim3(RT, 2), 256, 0, stream>>>(aggB, H1, wb2l, wb2r, H2, N, 256);

    // --- layer 3: single combined GEMM (cols 0-47 = Wl3 path, 48-95 = Wr3 path) ---
    gemm_mfma<3><<<391, 256, 0, stream>>>(H2, wb3, TR, N, 256, 96);
    final_fused<<<(N + 3) / 4, 256, 0, stream>>>(rowptr, csr_src, TR, dinv, out, N);
}

// Round 7
// 315.692 us; speedup vs baseline: 1.7018x; 1.7018x over previous
//
#include <hip/hip_runtime.h>
#include <hip/hip_bf16.h>

typedef __bf16 bf16_t;
typedef __bf16 bf16x8 __attribute__((ext_vector_type(8)));
typedef __bf16 bf16x4 __attribute__((ext_vector_type(4)));
typedef float f32x4 __attribute__((ext_vector_type(4)));

#define NN 50000
#define NE 600000

__device__ __forceinline__ void gload_lds16(const void* g, void* l) {
    __builtin_amdgcn_global_load_lds(
        (const __attribute__((address_space(1))) void*)g,
        (__attribute__((address_space(3))) void*)l, 16, 0, 0);
}

// ---------- converts ----------
// x fp32 -> bf16, and zero degi (saves a memset dispatch)
__global__ void cvt_x_zero(const float* __restrict__ in, bf16_t* __restrict__ out, int n4,
                           int* __restrict__ degi, int nz) {
    int t = blockIdx.x * blockDim.x + threadIdx.x;
    if (t < nz) degi[t] = 0;
    if (t >= n4) return;
    float4 v = ((const float4*)in)[t];
    bf16x4 o; o[0] = (bf16_t)v.x; o[1] = (bf16_t)v.y; o[2] = (bf16_t)v.z; o[3] = (bf16_t)v.w;
    ((bf16x4*)out)[t] = o;
}

// weights: W1/W2 pairs + combined W3 (96x256: rows 0-46 Wl3, 47 zero, 48-94 Wr3, 95 zero)
__global__ void cvt_weights(const float* __restrict__ Wl1, const float* __restrict__ Wr1,
                            const float* __restrict__ Wl2, const float* __restrict__ Wr2,
                            const float* __restrict__ Wl3, const float* __restrict__ Wr3,
                            bf16_t* __restrict__ o1l, bf16_t* __restrict__ o1r,
                            bf16_t* __restrict__ o2l, bf16_t* __restrict__ o2r,
                            bf16_t* __restrict__ o3) {
    int t = blockIdx.x * blockDim.x + threadIdx.x;  // 55296 groups of 4
    bf16x4 o;
    if (t < 49152) {
        const float* in; bf16_t* out; int g;
        if (t < 8192)       { in = Wl1; out = o1l; g = t; }
        else if (t < 16384) { in = Wr1; out = o1r; g = t - 8192; }
        else if (t < 32768) { in = Wl2; out = o2l; g = t - 16384; }
        else                { in = Wr2; out = o2r; g = t - 32768; }
        float4 v = ((const float4*)in)[g];
        o[0] = (bf16_t)v.x; o[1] = (bf16_t)v.y; o[2] = (bf16_t)v.z; o[3] = (bf16_t)v.w;
        ((bf16x4*)out)[g] = o;
    } else if (t < 55296) {
        int g = t - 49152;
        int row = g >> 6, c4 = (g & 63) * 4;  // row in [0,96)
        const float* src = nullptr;
        int srow = 0;
        if (row < 47) { src = Wl3; srow = row; }
        else if (row >= 48 && row < 95) { src = Wr3; srow = row - 48; }
        if (src) {
            float4 v = *(const float4*)(src + srow * 256 + c4);
            o[0] = (bf16_t)v.x; o[1] = (bf16_t)v.y; o[2] = (bf16_t)v.z; o[3] = (bf16_t)v.w;
        } else {
            o[0] = o[1] = o[2] = o[3] = (bf16_t)0.f;
        }
        *(bf16x4*)(o3 + row * 256 + c4) = o;
    }
}

// ---------- CSR build ----------
__global__ void deg_count(const int* __restrict__ ei, int* __restrict__ degi, int E) {
    int e = blockIdx.x * blockDim.x + threadIdx.x;
    if (e < E) atomicAdd(&degi[ei[E + e]], 1);
}

__global__ __launch_bounds__(1024) void scan_blocks(const int* __restrict__ degi,
                                                    int* __restrict__ rowptr,
                                                    float* __restrict__ dinv,
                                                    int* __restrict__ partials, int n) {
    int i = blockIdx.x * 1024 + threadIdx.x;
    int v = (i < n) ? degi[i] : 0;
    int lane = threadIdx.x & 63;
    int w = threadIdx.x >> 6;
    int s = v;
#pragma unroll
    for (int o = 1; o < 64; o <<= 1) {
        int t = __shfl_up(s, o);
        if (lane >= o) s += t;
    }
    __shared__ int wsum[16];
    if (lane == 63) wsum[w] = s;
    __syncthreads();
    if (threadIdx.x < 16) {
        int t = wsum[threadIdx.x];
#pragma unroll
        for (int o = 1; o < 16; o <<= 1) {
            int u = __shfl_up(t, o);
            if ((int)threadIdx.x >= o) t += u;
        }
        wsum[threadIdx.x] = t;
    }
    __syncthreads();
    int incl = s + ((w > 0) ? wsum[w - 1] : 0);
    if (i < n) {
        rowptr[i] = incl - v;
        dinv[i] = 1.0f / fmaxf((float)v, 1.0f);
    }
    if (threadIdx.x == 1023) partials[blockIdx.x] = incl;
}

__global__ void scan_partials(const int* __restrict__ partials, int* __restrict__ blockofs,
                              int* __restrict__ rowptr, int nb, int n) {
    int lane = threadIdx.x;
    int v = (lane < nb) ? partials[lane] : 0;
    int s = v;
#pragma unroll
    for (int o = 1; o < 64; o <<= 1) {
        int t = __shfl_up(s, o);
        if (lane >= o) s += t;
    }
    if (lane < nb) blockofs[lane] = s - v;
    if (lane == 63) rowptr[n] = s;
}

__global__ void add_offsets(int* __restrict__ rowptr, int* __restrict__ cursor,
                            const int* __restrict__ blockofs, int n) {
    int i = blockIdx.x * blockDim.x + threadIdx.x;
    if (i >= n) return;
    int v = rowptr[i] + blockofs[i >> 10];
    rowptr[i] = v;
    cursor[i] = v;
}

__global__ void fill_csr(const int* __restrict__ ei, int* __restrict__ cursor,
                         int* __restrict__ csr_src, int E) {
    int e = blockIdx.x * blockDim.x + threadIdx.x;
    if (e >= E) return;
    int d = ei[E + e];
    int pos = atomicAdd(&cursor[d], 1);
    csr_src[pos] = ei[e];
}

// ---------- gather aggregations (half-wave per dst node, 2 dst/wave) ----------
// C=128 bf16 source (xB). 32 lanes x bf16x4 (8B) = full 256B row per iter.
__global__ void gather_agg_128(const int* __restrict__ rowptr, const int* __restrict__ csr_src,
                               const bf16_t* __restrict__ X, const float* __restrict__ dinv,
                               bf16_t* __restrict__ out, int N) {
    int wv = blockIdx.x * (blockDim.x >> 6) + (threadIdx.x >> 6);
    int lane = threadIdx.x & 63;
    int node = wv * 2 + (lane >> 5);
    if (node >= N) return;
    int sub = lane & 31;
    int c = sub * 4;
    int s0 = rowptr[node], s1 = rowptr[node + 1];
    float acc[4] = {0.f, 0.f, 0.f, 0.f};
    int j = s0;
    for (; j + 3 < s1; j += 4) {
        int sa = csr_src[j], sb = csr_src[j + 1], sc = csr_src[j + 2], sd = csr_src[j + 3];
        bf16x4 va = *(const bf16x4*)(X + (long)sa * 128 + c);
        bf16x4 vb = *(const bf16x4*)(X + (long)sb * 128 + c);
        bf16x4 vc = *(const bf16x4*)(X + (long)sc * 128 + c);
        bf16x4 vd = *(const bf16x4*)(X + (long)sd * 128 + c);
#pragma unroll
        for (int i = 0; i < 4; i++)
            acc[i] += ((float)va[i] + (float)vb[i]) + ((float)vc[i] + (float)vd[i]);
    }
    for (; j < s1; j++) {
        int sa = csr_src[j];
        bf16x4 va = *(const bf16x4*)(X + (long)sa * 128 + c);
#pragma unroll
        for (int i = 0; i < 4; i++) acc[i] += (float)va[i];
    }
    float di = dinv[node];
    bf16x4 o;
#pragma unroll
    for (int i = 0; i < 4; i++) o[i] = (bf16_t)(acc[i] * di);
    *(bf16x4*)(out + (long)node * 128 + c) = o;
}

// C=256 bf16 source. 32 lanes x bf16x8 (16B) = full 512B row per iter.
__global__ void gather_agg_256(const int* __restrict__ rowptr, const int* __restrict__ csr_src,
                               const bf16_t* __restrict__ H, const float* __restrict__ dinv,
                               bf16_t* __restrict__ out, int N) {
    int wv = blockIdx.x * (blockDim.x >> 6) + (threadIdx.x >> 6);
    int lane = threadIdx.x & 63;
    int node = wv * 2 + (lane >> 5);
    if (node >= N) return;
    int sub = lane & 31;
    int c = sub * 8;
    int s0 = rowptr[node], s1 = rowptr[node + 1];
    float acc[8] = {0.f, 0.f, 0.f, 0.f, 0.f, 0.f, 0.f, 0.f};
    int j = s0;
    for (; j + 1 < s1; j += 2) {
        int sa = csr_src[j], sb = csr_src[j + 1];
        bf16x8 va = *(const bf16x8*)(H + (long)sa * 256 + c);
        bf16x8 vb = *(const bf16x8*)(H + (long)sb * 256 + c);
#pragma unroll
        for (int i = 0; i < 8; i++) acc[i] += (float)va[i] + (float)vb[i];
    }
    if (j < s1) {
        int sa = csr_src[j];
        bf16x8 va = *(const bf16x8*)(H + (long)sa * 256 + c);
#pragma unroll
        for (int i = 0; i < 8; i++) acc[i] += (float)va[i];
    }
    float di = dinv[node];
    bf16x8 o;
#pragma unroll
    for (int i = 0; i < 8; i++) o[i] = (bf16_t)(acc[i] * di);
    *(bf16x8*)(out + (long)node * 256 + c) = o;
}

// ---------- LDS-staged MFMA GEMM: 128x128 tile / block, BK=64 slices ----------
template <int KTOT, bool DUAL, bool RELU>
__global__ __launch_bounds__(256) void gemm_lds(
    const bf16_t* __restrict__ A1, const bf16_t* __restrict__ A2,
    const bf16_t* __restrict__ W1, const bf16_t* __restrict__ W2,
    bf16_t* __restrict__ Out, int N, int NOUT) {
    __shared__ bf16_t As[128 * 64];
    __shared__ bf16_t Bs[128 * 64];
    int tid = threadIdx.x;
    int w = tid >> 6, lane = tid & 63;
    int wr = w >> 1, wc = w & 1;
    int rowBase = blockIdx.x * 128;
    int colBase = blockIdx.y * 128;
    int m = lane & 15, q = lane >> 4;

    long aoff[4], boff[4];
    int ldsOff[4];
#pragma unroll
    for (int i = 0; i < 4; i++) {
        int c = w * 256 + i * 64 + lane;
        int r = c >> 3, s = c & 7;
        int gk = (s ^ (r & 7)) << 3;
        aoff[i] = (long)min(rowBase + r, N - 1) * KTOT + gk;
        boff[i] = (long)(colBase + r) * KTOT + gk;
        ldsOff[i] = (w * 4 + i) * 512;
    }

    f32x4 acc[4][4];
#pragma unroll
    for (int a = 0; a < 4; a++)
#pragma unroll
        for (int b = 0; b < 4; b++) acc[a][b] = (f32x4){0.f, 0.f, 0.f, 0.f};

#pragma unroll
    for (int half = 0; half < (DUAL ? 2 : 1); half++) {
        const bf16_t* A = half ? A2 : A1;
        const bf16_t* W = half ? W2 : W1;
#pragma unroll
        for (int k0 = 0; k0 < KTOT; k0 += 64) {
            __syncthreads();
#pragma unroll
            for (int i = 0; i < 4; i++) {
                gload_lds16(A + aoff[i] + k0, As + ldsOff[i]);
                gload_lds16(W + boff[i] + k0, Bs + ldsOff[i]);
            }
            __syncthreads();
#pragma unroll
            for (int ks = 0; ks < 2; ks++) {
                bf16x8 af[4], bfr[4];
#pragma unroll
                for (int rf = 0; rf < 4; rf++) {
                    int r = wr * 64 + rf * 16 + m;
                    int seg = ks * 4 + q;
                    af[rf] = *(const bf16x8*)(As + r * 64 + ((seg ^ (r & 7)) << 3));
                }
#pragma unroll
                for (int cf = 0; cf < 4; cf++) {
                    int r = wc * 64 + cf * 16 + m;
                    int seg = ks * 4 + q;
                    bfr[cf] = *(const bf16x8*)(Bs + r * 64 + ((seg ^ (r & 7)) << 3));
                }
#pragma unroll
                for (int rf = 0; rf < 4; rf++)
#pragma unroll
                    for (int cf = 0; cf < 4; cf++)
                        acc[rf][cf] = __builtin_amdgcn_mfma_f32_16x16x32_bf16(af[rf], bfr[cf], acc[rf][cf], 0, 0, 0);
            }
        }
    }

    int r0 = q * 4;
#pragma unroll
    for (int rf = 0; rf < 4; rf++) {
#pragma unroll
        for (int i = 0; i < 4; i++) {
            int row = rowBase + wr * 64 + rf * 16 + r0 + i;
            if (row >= N) continue;
#pragma unroll
            for (int cf = 0; cf < 4; cf++) {
                float v = acc[rf][cf][i];
                if (RELU) v = fmaxf(v, 0.f);
                Out[(long)row * NOUT + colBase + wc * 64 + cf * 16 + m] = (bf16_t)v;
            }
        }
    }
}

// ---------- direct-load MFMA GEMM (layer 3: combined NOUT=96, bf16 out) ----------
template <int CF>
__global__ __launch_bounds__(256) void gemm_mfma(
    const bf16_t* __restrict__ A1, const bf16_t* __restrict__ W1,
    bf16_t* __restrict__ Out, int N, int K, int NOUT) {
    const int G = NOUT / (16 * CF);
    int lane = threadIdx.x & 63;
    int wid = blockIdx.x * 4 + (threadIdx.x >> 6);
    int rowTile = wid / G;
    int cg = wid - rowTile * G;
    int rowBase = rowTile * 64;
    if (rowBase >= N) return;
    int colBase = cg * 16 * CF;
    int m = lane & 15;
    int kq = (lane >> 4) * 8;

    f32x4 acc[4][CF];
#pragma unroll
    for (int a = 0; a < 4; a++)
#pragma unroll
        for (int b = 0; b < CF; b++) acc[a][b] = (f32x4){0.f, 0.f, 0.f, 0.f};

    long ar[4];
#pragma unroll
    for (int rf = 0; rf < 4; rf++) {
        int r = rowBase + rf * 16 + m;
        ar[rf] = (long)min(r, N - 1) * K;
    }

    for (int k0 = kq; k0 < K; k0 += 32) {
        bf16x8 a[4], b[CF];
#pragma unroll
        for (int rf = 0; rf < 4; rf++) a[rf] = *(const bf16x8*)(A1 + ar[rf] + k0);
#pragma unroll
        for (int cf = 0; cf < CF; cf++)
            b[cf] = *(const bf16x8*)(W1 + (long)(colBase + cf * 16 + m) * K + k0);
#pragma unroll
        for (int rf = 0; rf < 4; rf++)
#pragma unroll
            for (int cf = 0; cf < CF; cf++)
                acc[rf][cf] = __builtin_amdgcn_mfma_f32_16x16x32_bf16(a[rf], b[cf], acc[rf][cf], 0, 0, 0);
    }

    int r0 = (lane >> 4) * 4;
#pragma unroll
    for (int rf = 0; rf < 4; rf++) {
#pragma unroll
        for (int i = 0; i < 4; i++) {
            int row = rowBase + rf * 16 + r0 + i;
            if (row >= N) continue;
#pragma unroll
            for (int cf = 0; cf < CF; cf++)
                Out[(long)row * NOUT + colBase + cf * 16 + m] = (bf16_t)acc[rf][cf][i];
        }
    }
}

// ---------- final: gather TR[:, :48] + dinv + TR[node, 48+lane] + log_softmax ----------
__global__ void final_fused(const int* __restrict__ rowptr, const int* __restrict__ csr_src,
                            const bf16_t* __restrict__ TR, const float* __restrict__ dinv,
                            float* __restrict__ out, int N) {
    int wid = blockIdx.x * (blockDim.x >> 6) + (threadIdx.x >> 6);
    int lane = threadIdx.x & 63;
    if (wid >= N) return;
    int s0 = rowptr[wid], s1 = rowptr[wid + 1];
    float a = 0.f, b = 0.f;
    if (lane < 48) {
        int j = s0;
        for (; j + 3 < s1; j += 4) {
            int sa = csr_src[j], sb = csr_src[j + 1], sc = csr_src[j + 2], sd = csr_src[j + 3];
            a += (float)TR[(long)sa * 96 + lane] + (float)TR[(long)sb * 96 + lane];
            b += (float)TR[(long)sc * 96 + lane] + (float)TR[(long)sd * 96 + lane];
        }
        for (; j < s1; j++) a += (float)TR[(long)csr_src[j] * 96 + lane];
    }
    bool act = lane < 47;
    float v = act ? (a + b) * dinv[wid] + (float)TR[(long)wid * 96 + 48 + lane] : -INFINITY;
    float mx = v;
#pragma unroll
    for (int o = 32; o; o >>= 1) mx = fmaxf(mx, __shfl_xor(mx, o));
    float ex = act ? expf(v - mx) : 0.f;
    float s = ex;
#pragma unroll
    for (int o = 32; o; o >>= 1) s += __shfl_xor(s, o);
    float ls = logf(s);
    if (act) out[(long)wid * 47 + lane] = v - mx - ls;
}

extern "C" void kernel_launch(void* const* d_in, const int* in_sizes, int n_in,
                              void* d_out, int out_size, void* d_ws, size_t ws_size,
                              hipStream_t stream) {
    const float* x   = (const float*)d_in[0];
    const float* Wl1 = (const float*)d_in[1];
    const float* Wr1 = (const float*)d_in[2];
    const float* Wl2 = (const float*)d_in[3];
    const float* Wr2 = (const float*)d_in[4];
    const float* Wl3 = (const float*)d_in[5];
    const float* Wr3 = (const float*)d_in[6];
    const int*   ei  = (const int*)d_in[7];
    float* out = (float*)d_out;
    const int N = NN, E = NE;
    const int NB = (N + 1023) / 1024;

    char* ws = (char*)d_ws;
    size_t off = 0;
    auto carve = [&](size_t bytes) { void* p = ws + off; off = (off + bytes + 255) & ~(size_t)255; return p; };
    int*    degi     = (int*)carve((size_t)N * 4);
    int*    rowptr   = (int*)carve((size_t)(N + 1) * 4);
    int*    cursor   = (int*)carve((size_t)N * 4);
    int*    csr_src  = (int*)carve((size_t)E * 4);
    int*    partials = (int*)carve(64 * 4);
    int*    blockofs = (int*)carve(64 * 4);
    float*  dinv     = (float*)carve((size_t)N * 4);
    bf16_t* aggB     = (bf16_t*)carve((size_t)N * 256 * 2);
    bf16_t* xB       = (bf16_t*)carve((size_t)N * 128 * 2);
    bf16_t* H1       = (bf16_t*)carve((size_t)N * 256 * 2);
    bf16_t* H2       = (bf16_t*)carve((size_t)N * 256 * 2);
    bf16_t* TR       = (bf16_t*)carve((size_t)N * 96 * 2);
    bf16_t* wb1l = (bf16_t*)carve(256 * 128 * 2);
    bf16_t* wb1r = (bf16_t*)carve(256 * 128 * 2);
    bf16_t* wb2l = (bf16_t*)carve(256 * 256 * 2);
    bf16_t* wb2r = (bf16_t*)carve(256 * 256 * 2);
    bf16_t* wb3  = (bf16_t*)carve(96 * 256 * 2);

    // --- converts (+degi zeroing) ---
    cvt_x_zero<<<(N * 32 + 255) / 256, 256, 0, stream>>>(x, xB, N * 32, degi, N);
    cvt_weights<<<216, 256, 0, stream>>>(Wl1, Wr1, Wl2, Wr2, Wl3, Wr3,
                                         wb1l, wb1r, wb2l, wb2r, wb3);

    // --- CSR build ---
    deg_count<<<(E + 255) / 256, 256, 0, stream>>>(ei, degi, E);
    scan_blocks<<<NB, 1024, 0, stream>>>(degi, rowptr, dinv, partials, N);
    scan_partials<<<1, 64, 0, stream>>>(partials, blockofs, rowptr, NB, N);
    add_offsets<<<(N + 255) / 256, 256, 0, stream>>>(rowptr, cursor, blockofs, N);
    fill_csr<<<(E + 255) / 256, 256, 0, stream>>>(ei, cursor, csr_src, E);

    const int RT = (N + 127) / 128;

    // --- layer 1 ---
    gather_agg_128<<<(N / 2 + 3) / 4, 256, 0, stream>>>(rowptr, csr_src, xB, dinv, aggB, N);
    gemm_lds<128, true, true><<<dim3(RT, 2), 256, 0, stream>>>(aggB, xB, wb1l, wb1r, H1, N, 256);

    // --- layer 2 ---
    gather_agg_256<<<(N / 2 + 3) / 4, 256, 0, stream>>>(rowptr, csr_src, H1, dinv, aggB, N);
    gemm_lds<256, true, true><<<dim3(RT, 2), 256, 0, stream>>>(aggB, H1, wb2l, wb2r, H2, N, 256);

    // --- layer 3: single combined GEMM (cols 0-47 = Wl3 path, 48-95 = Wr3 path) ---
    gemm_mfma<3><<<391, 256, 0, stream>>>(H2, wb3, TR, N, 256, 96);
    final_fused<<<(N + 3) / 4, 256, 0, stream>>>(rowptr, csr_src, TR, dinv, out, N);
}